// Round 16
// baseline (127.941 us; speedup 1.0000x reference)
//
#include <hip/hip_runtime.h>
#include <stdint.h>

// Croston's method: B=8192 series x T=2048 steps. out = Z'/V' per step.
//
// Round 27: PACKED-FP32 two-series-per-wave scan (v_pk_fma_f32 path).
// R19-R26 synthesis: nothing saturated (VALU 24-30%, DS ~25%, HBM ~48%
// of fair share, occupancy 8-32 waves/CU all neutral) and 6 overlap
// attempts null -> serial-path-bound: each wave's per-series critical
// path is ~2000+ cycles of issue-serial fold/scan/replay work. The one
// untouched lever: halve the instruction stream. CDNA4 has packed FP32
// (v_pk_fma/mul/add_f32): <2 x float> expressions emit one inst for two
// ops. Two series per wave, element-packed; selects replaced by EXACT
// multiply-gating so everything is packable:
//   z  = 1 - min(xt,1)        (xt in {0,1,2} exactly -> z in {0,1})
//   wa = a - z*a               z=1 -> 0 EXACT; z=0 -> a EXACT
//   m  = 1 - wa                -> 1 EXACT or ma (= fl(1-a)) EXACT
//   az=m*az; bz=m*bz+a*xt; r=m*r+wa*f; s=m*s+wa*g; f=z*f; g=z*g+1
// Bit-identical to the cndmask version in BOTH branches (zero case
// multiplies by exact 1.0 / adds exact 0.0; nz case same fma forms) ->
// absmax must stay exactly 0.0078125. Transposes stay R19-verbatim
// (per-series through the same 8KB buffer; in-order DS pipe handles the
// A-read/B-write alias). Shuffles per-component (count/series unchanged).
// If null: VALU issue exonerated; revert R20, declare roofline.

#define TLEN 2048

typedef float vf4 __attribute__((ext_vector_type(4)));
typedef float vf2 __attribute__((ext_vector_type(2)));

__global__ __launch_bounds__(256) void croston_kernel(
    const float* __restrict__ x,
    const float* __restrict__ alpha,
    const float* __restrict__ Z0,
    const float* __restrict__ V0,
    const float* __restrict__ q0,
    float* __restrict__ out)
{
    __shared__ __attribute__((aligned(16))) float lds[4][2048]; // 8KB/wave

    const int warp = threadIdx.x >> 6;
    const int lane = threadIdx.x & 63;
    const int wave = blockIdx.x * 4 + warp;   // 0..4095
    const int widA = wave * 2;                // packed pair of series
    const int widB = widA + 1;
    float* W = lds[warp];                     // wave-private

    const float a = alpha[0];

    // R19 transpose addressing (verified):
    const int rg   = lane >> 3;
    const int e    = (lane & 7) ^ rg;
    const int goff = rg * 32 + (e << 2);      // + j*256
    const int l7   = lane & 7;
    const int lbase = lane * 32;

    // ---- issue ALL loads upfront (A then B; counted vmcnt consumes A first) ----
    vf4 ldA[8], ldB[8];
#pragma unroll
    for (int j = 0; j < 8; ++j)
        ldA[j] = *(const vf4*)(x + (size_t)widA * TLEN + j * 256 + lane * 4);
#pragma unroll
    for (int j = 0; j < 8; ++j)
        ldB[j] = *(const vf4*)(x + (size_t)widB * TLEN + j * 256 + lane * 4);

    vf2 Zv = {Z0[widA], Z0[widB]};
    vf2 Vv = {V0[widA], V0[widB]};
    vf2 qv = {q0[widA], q0[widB]};

    // ---- transpose A, then B (same buffer; per-wave DS pipe is in-order) ----
#pragma unroll
    for (int j = 0; j < 8; ++j) *(vf4*)(W + j * 256 + goff) = ldA[j];
    vf4 xvA[8];
#pragma unroll
    for (int m = 0; m < 8; ++m) xvA[m] = *(const vf4*)(W + lbase + ((m ^ l7) << 2));
#pragma unroll
    for (int j = 0; j < 8; ++j) *(vf4*)(W + j * 256 + goff) = ldB[j];
    vf4 xvB[8];
#pragma unroll
    for (int m = 0; m < 8; ++m) xvB[m] = *(const vf4*)(W + lbase + ((m ^ l7) << 2));

    const vf2 v1 = {1.f, 1.f};
    const vf2 v0 = {0.f, 0.f};

    // ---- packed fold: compose 32 per-step affine maps for BOTH series ----
    vf2 az = v1, bz = v0, rr = v0, ss = v0, ff = v1, gg = v0;
#pragma unroll
    for (int m = 0; m < 8; ++m) {
#pragma unroll
        for (int k = 0; k < 4; ++k) {
            const vf2 xt = {xvA[m][k], xvB[m][k]};
            const vf2 z  = v1 - __builtin_elementwise_min(xt, v1);
            const vf2 wa = a - z * a;     // exact: 0 (zero) or a (nz)
            const vf2 mm = v1 - wa;       // exact: 1 or ma
            const vf2 axt = a * xt;       // exact 0 when xt==0
            az = mm * az;
            bz = mm * bz + axt;
            rr = mm * rr + wa * ff;       // old ff
            ss = mm * ss + wa * gg;       // old gg
            ff = z * ff;
            gg = z * gg + v1;
        }
    }

    // ---- inclusive Hillis-Steele compose scan (packed; shuffles per comp) ----
#pragma unroll
    for (int d = 1; d < 64; d <<= 1) {
        vf2 az_o, bz_o, r_o, s_o, f_o, g_o;
        az_o.x = __shfl_up(az.x, d); az_o.y = __shfl_up(az.y, d);
        bz_o.x = __shfl_up(bz.x, d); bz_o.y = __shfl_up(bz.y, d);
        r_o.x  = __shfl_up(rr.x, d); r_o.y  = __shfl_up(rr.y, d);
        s_o.x  = __shfl_up(ss.x, d); s_o.y  = __shfl_up(ss.y, d);
        f_o.x  = __shfl_up(ff.x, d); f_o.y  = __shfl_up(ff.y, d);
        g_o.x  = __shfl_up(gg.x, d); g_o.y  = __shfl_up(gg.y, d);
        if (lane >= d) {
            bz = az * bz_o + bz;
            ss = az * s_o + (rr * g_o + ss);   // old rr
            rr = az * r_o + rr * f_o;
            az = az * az_o;
            gg = ff * g_o + gg;                 // old ff
            ff = ff * f_o;
        }
    }

    // ---- exclusive prefix (shift one lane; identity at lane 0) ----
    vf2 azE, bzE, rE, sE, fE, gE;
    azE.x = __shfl_up(az.x, 1); azE.y = __shfl_up(az.y, 1);
    bzE.x = __shfl_up(bz.x, 1); bzE.y = __shfl_up(bz.y, 1);
    rE.x  = __shfl_up(rr.x, 1); rE.y  = __shfl_up(rr.y, 1);
    sE.x  = __shfl_up(ss.x, 1); sE.y  = __shfl_up(ss.y, 1);
    fE.x  = __shfl_up(ff.x, 1); fE.y  = __shfl_up(ff.y, 1);
    gE.x  = __shfl_up(gg.x, 1); gE.y  = __shfl_up(gg.y, 1);
    if (lane == 0) {
        azE = v1; bzE = v0; rE = v0; sE = v0; fE = v1; gE = v0;
    }

    // ---- state at this lane's window start (exact) ----
    vf2 Zc = azE * Zv + bzE;
    vf2 Vc = azE * Vv + (rE * qv + sE);
    vf2 qc = fE * qv + gE;

    // ---- packed replay: 32 steps, emit out = Z'/V' for both series ----
#pragma unroll
    for (int m = 0; m < 8; ++m) {
#pragma unroll
        for (int k = 0; k < 4; ++k) {
            const vf2 xt = {xvA[m][k], xvB[m][k]};
            const vf2 z  = v1 - __builtin_elementwise_min(xt, v1);
            const vf2 wa = a - z * a;
            const vf2 mm = v1 - wa;
            const vf2 axt = a * xt;
            Zc = mm * Zc + axt;
            Vc = mm * Vc + wa * qc;
            qc = z * qc + v1;
            xvA[m][k] = Zc.x * __builtin_amdgcn_rcpf(Vc.x);
            xvB[m][k] = Zc.y * __builtin_amdgcn_rcpf(Vc.y);
        }
    }

    // ---- transpose-out + coalesced stores, A then B (R19 verbatim) ----
#pragma unroll
    for (int m = 0; m < 8; ++m) *(vf4*)(W + lbase + ((m ^ l7) << 2)) = xvA[m];
#pragma unroll
    for (int j = 0; j < 8; ++j) {
        const vf4 o = *(const vf4*)(W + j * 256 + goff);
        *(vf4*)(out + (size_t)widA * TLEN + j * 256 + lane * 4) = o;
    }
#pragma unroll
    for (int m = 0; m < 8; ++m) *(vf4*)(W + lbase + ((m ^ l7) << 2)) = xvB[m];
#pragma unroll
    for (int j = 0; j < 8; ++j) {
        const vf4 o = *(const vf4*)(W + j * 256 + goff);
        *(vf4*)(out + (size_t)widB * TLEN + j * 256 + lane * 4) = o;
    }
}

extern "C" void kernel_launch(void* const* d_in, const int* in_sizes, int n_in,
                              void* d_out, int out_size, void* d_ws, size_t ws_size,
                              hipStream_t stream) {
    const float* x     = (const float*)d_in[0];
    const float* alpha = (const float*)d_in[1];
    const float* Z0    = (const float*)d_in[2];
    const float* V0    = (const float*)d_in[3];
    const float* q0    = (const float*)d_in[4];
    float* out = (float*)d_out;

    // 4096 waves = one packed PAIR of series each; 1024 blocks x 4 waves,
    // 32KB LDS/block.
    dim3 block(256);
    dim3 grid(1024);
    croston_kernel<<<grid, block, 0, stream>>>(x, alpha, Z0, V0, q0, out);
}

// Round 17
// 117.819 us; speedup vs baseline: 1.0859x; 1.0859x over previous
//
#include <hip/hip_runtime.h>
#include <stdint.h>

// Croston's method: B=8192 series x T=2048 steps. out = Z'/V' per step.
//
// Round 28: REVERT to Round 20 (the best verified kernel, 118.62us) after
// R27's decisive negative: packing halved VALUBusy (24->13.2%, counter-
// confirmed) yet croston went 33->57us -- VALU issue exonerated; VGPR=164
// and 2 dispatch rounds hurt. Session synthesis (13 experiments): only
// R19's access-shape fix (per-instruction coalescing + swizzled LDS
// transpose) was a real win (+8us). Staging mechanism, occupancy 4-32
// waves/CU, 6 overlap schemes, NT stores (refuted 2x), sched fences
// (full + surgical 0x387), and instruction count were all individually
// tested: null or negative. The scan family sits at ~33us for ~101MB
// (~3 TB/s effective) with NO saturated counter -- a service-rate floor
// of the latency-chained read->transform->write stream. Remaining bench
// time (~85us) is harness poison fills.
//
// Structure (R20, verified 118.62us): one wave per series; series split
// into two sequential 1024-step scans (EXACT: state at t=1024 = lane63's
// inclusive map applied to initial state, __shfl broadcast). 4KB/wave
// swizzled transpose buffer -> 16KB/block -> 32 waves/CU. H2 global
// loads issued before H1's scan (fly under fold+scan+replay); H1 stores
// drain under H2 compute. Scan params: p==az reduction (Z,V share decay).
// 4KB layout (per half, 1024 floats, 32-float rows): granule G=t/4,
// owner lane lo=G>>2, slot m=G&3, row=lo>>1, halfbit=lo&1;
// phys quad = ((halfbit<<2)|m) ^ (row&7); every wave64 b128 LDS phase
// covers all 8 bank-quads per lane-octet (structural floor, verified).

#define TLEN 2048
#define HALF 1024

typedef float vf4 __attribute__((ext_vector_type(4)));

__global__ __launch_bounds__(256) void croston_kernel(
    const float* __restrict__ x,
    const float* __restrict__ alpha,
    const float* __restrict__ Z0,
    const float* __restrict__ V0,
    const float* __restrict__ q0,
    float* __restrict__ out)
{
    __shared__ __attribute__((aligned(16))) float lds[4][HALF]; // 4KB/wave

    const int warp = threadIdx.x >> 6;
    const int lane = threadIdx.x & 63;
    const int wid  = blockIdx.x * 4 + warp;   // series id, 0..8191
    float* W = lds[warp];                     // wave-private

    const float a  = alpha[0];
    const float ma = 1.0f - a;

    // granule-side (load/store) transpose address: inst j adds j*8 rows
    const int rg  = lane >> 3;                               // row-in-inst
    const int pqg = ((((lane >> 2) & 1) << 2) | (lane & 3)) ^ ((lane >> 3) & 7);
    const int goff = rg * 32 + pqg * 4;                      // + j*256

    // lane-side (scan window) transpose address: slot m
    const int rowl = lane >> 1;
    const int lbase = rowl * 32;
    const int lkey  = rowl & 7;
    const int lhalf = (lane & 1) << 2;

    auto lane_off = [&](int m) { return lbase + (((lhalf | m) ^ lkey) << 2); };

    // ---- associative scan over one 1024-step half ----
    auto scan_half = [&](vf4* xv, float& Zs, float& Vs, float& qs) {
        // fold: compose 16 per-step affine maps (p dropped: p == az)
        float az = 1.f, bz = 0.f, r = 0.f, s = 0.f, f = 1.f, g = 0.f;
#pragma unroll
        for (int m = 0; m < 4; ++m) {
#pragma unroll
            for (int k = 0; k < 4; ++k) {
                const float xt = xv[m][k];
                const bool  nz = (xt != 0.f);
                const float az_n = ma * az;
                const float bz_n = fmaf(ma, bz, a * xt);
                const float r_n  = fmaf(ma, r, a * f);
                const float s_n  = fmaf(ma, s, a * g);
                az = nz ? az_n : az;
                bz = nz ? bz_n : bz;
                r  = nz ? r_n  : r;
                s  = nz ? s_n  : s;
                g  = nz ? 1.f  : (g + 1.f);   // r_n,s_n already took old f,g
                f  = nz ? 0.f  : f;
            }
        }
        // inclusive Hillis-Steele compose scan across 64 lanes
#pragma unroll
        for (int d = 1; d < 64; d <<= 1) {
            const float az_o = __shfl_up(az, d);
            const float bz_o = __shfl_up(bz, d);
            const float r_o  = __shfl_up(r,  d);
            const float s_o  = __shfl_up(s,  d);
            const float f_o  = __shfl_up(f,  d);
            const float g_o  = __shfl_up(g,  d);
            if (lane >= d) {
                bz = fmaf(az, bz_o, bz);
                s  = fmaf(az, s_o, fmaf(r, g_o, s));
                r  = fmaf(az, r_o, r * f_o);
                az = az * az_o;
                g  = fmaf(f, g_o, g);
                f  = f * f_o;
            }
        }
        // totals (lane 63 inclusive) -> exact state at half end
        const float azT = __shfl(az, 63), bzT = __shfl(bz, 63);
        const float rT  = __shfl(r, 63),  sT  = __shfl(s, 63);
        const float fT  = __shfl(f, 63),  gT  = __shfl(g, 63);
        const float Ze = fmaf(azT, Zs, bzT);
        const float Ve = fmaf(azT, Vs, fmaf(rT, qs, sT));
        const float qe = fmaf(fT, qs, gT);
        // exclusive prefix (shift one lane; identity at lane 0)
        float azE = __shfl_up(az, 1), bzE = __shfl_up(bz, 1);
        float rE  = __shfl_up(r, 1),  sE  = __shfl_up(s, 1);
        float fE  = __shfl_up(f, 1),  gE  = __shfl_up(g, 1);
        if (lane == 0) {
            azE = 1.f; bzE = 0.f; rE = 0.f; sE = 0.f; fE = 1.f; gE = 0.f;
        }
        // state at this lane's window start (exact)
        float Z = fmaf(azE, Zs, bzE);
        float V = fmaf(azE, Vs, fmaf(rE, qs, sE));
        float q = fmaf(fE, qs, gE);
        // replay 16 steps, emit out = Z'/V'
#pragma unroll
        for (int m = 0; m < 4; ++m) {
#pragma unroll
            for (int k = 0; k < 4; ++k) {
                const float xt = xv[m][k];
                const bool  nz = (xt != 0.f);
                const float Zn = fmaf(ma, Z, a * xt);
                const float Vn = fmaf(ma, V, a * q);
                Z = nz ? Zn : Z;
                V = nz ? Vn : V;
                q = nz ? 1.f : (q + 1.f);
                xv[m][k] = Z * __builtin_amdgcn_rcpf(V);
            }
        }
        Zs = Ze; Vs = Ve; qs = qe;
    };

    const float* row  = x   + (size_t)wid * TLEN;
    float*       orow = out + (size_t)wid * TLEN;

    float Zs = Z0[wid], Vs = V0[wid], qs = q0[wid];

    // ---- H1: load (coalesced 1KB/inst) -> transpose in ----
    vf4 ld[4];
#pragma unroll
    for (int j = 0; j < 4; ++j)
        ld[j] = *(const vf4*)(row + j * 256 + lane * 4);
#pragma unroll
    for (int j = 0; j < 4; ++j)
        *(vf4*)(W + j * 256 + goff) = ld[j];
    vf4 xv[4];
#pragma unroll
    for (int m = 0; m < 4; ++m)
        xv[m] = *(const vf4*)(W + lane_off(m));

    // ---- issue H2 loads now: they fly under H1 fold+scan+replay ----
#pragma unroll
    for (int j = 0; j < 4; ++j)
        ld[j] = *(const vf4*)(row + HALF + j * 256 + lane * 4);

    scan_half(xv, Zs, Vs, qs);

    // ---- H1 out: transpose out -> coalesced stores ----
#pragma unroll
    for (int m = 0; m < 4; ++m)
        *(vf4*)(W + lane_off(m)) = xv[m];
#pragma unroll
    for (int j = 0; j < 4; ++j) {
        const vf4 o = *(const vf4*)(W + j * 256 + goff);
        *(vf4*)(orow + j * 256 + lane * 4) = o;
    }

    // ---- H2: transpose in (WAR on W ordered by in-order DS pipe) ----
#pragma unroll
    for (int j = 0; j < 4; ++j)
        *(vf4*)(W + j * 256 + goff) = ld[j];
#pragma unroll
    for (int m = 0; m < 4; ++m)
        xv[m] = *(const vf4*)(W + lane_off(m));

    scan_half(xv, Zs, Vs, qs);

    // ---- H2 out ----
#pragma unroll
    for (int m = 0; m < 4; ++m)
        *(vf4*)(W + lane_off(m)) = xv[m];
#pragma unroll
    for (int j = 0; j < 4; ++j) {
        const vf4 o = *(const vf4*)(W + j * 256 + goff);
        *(vf4*)(orow + HALF + j * 256 + lane * 4) = o;
    }
}

extern "C" void kernel_launch(void* const* d_in, const int* in_sizes, int n_in,
                              void* d_out, int out_size, void* d_ws, size_t ws_size,
                              hipStream_t stream) {
    const float* x     = (const float*)d_in[0];
    const float* alpha = (const float*)d_in[1];
    const float* Z0    = (const float*)d_in[2];
    const float* V0    = (const float*)d_in[3];
    const float* q0    = (const float*)d_in[4];
    float* out = (float*)d_out;

    // 8192 waves = one per series; 256-thread blocks (4 series each).
    // 16KB LDS/block -> 32 waves/CU.
    dim3 block(256);
    dim3 grid(2048);
    croston_kernel<<<grid, block, 0, stream>>>(x, alpha, Z0, V0, q0, out);
}